// Round 3
// baseline (1221.330 us; speedup 1.0000x reference)
//
#include <hip/hip_runtime.h>
#include <cmath>

#define PI_D 3.14159265358979323846

static constexpr int B_ = 4, H_ = 128, W_ = 128, C_ = 768, WF = 65;
static constexpr size_t PLANE = (size_t)B_ * H_ * WF * C_;  // 25,559,040 elems
static constexpr float LAMBDA_ = 0.01f;

using short8   = __attribute__((ext_vector_type(8))) short;
using floatx16 = __attribute__((ext_vector_type(16))) float;

__device__ __forceinline__ float2 cmul(float2 a, float2 b) {
  return make_float2(a.x * b.x - a.y * b.y, a.x * b.y + a.y * b.x);
}
__device__ __forceinline__ unsigned short f2bfu(float f) {
  union { float f; unsigned u; } v; v.f = f;
  unsigned r = v.u + 0x7FFFu + ((v.u >> 16) & 1u);   // RNE
  return (unsigned short)(r >> 16);
}
__device__ __forceinline__ float bf2f(unsigned short u) {
  union { unsigned u; float f; } v; v.u = (unsigned)u << 16;
  return v.f;
}
__device__ __forceinline__ float softshrink(float v) {
  return v > LAMBDA_ ? v - LAMBDA_ : (v < -LAMBDA_ ? v + LAMBDA_ : 0.0f);
}

// ---------------- 64-pt complex FFT, fully unrolled, in registers ----------
template<int SIGN, int S>
__device__ __forceinline__ void fft64_stage(float2* z, const float2* tw) {
  constexpr int half = 1 << S;
  #pragma unroll
  for (int g = 0; g < 32; ++g) {
    const int j  = g & (half - 1);
    const int i0 = ((g >> S) << (S + 1)) + j;
    const int i1 = i0 + half;
    float2 w = tw[j << (5 - S)];
    if (SIGN > 0) w.y = -w.y;
    float2 t = cmul(w, z[i1]);
    float2 a = z[i0];
    z[i0] = make_float2(a.x + t.x, a.y + t.y);
    z[i1] = make_float2(a.x - t.x, a.y - t.y);
  }
}
template<int SIGN>
__device__ __forceinline__ void fft64(float2* z, const float2* tw) {
  #pragma unroll
  for (int i = 0; i < 64; ++i) {
    const int j = ((i >> 5) & 1) | (((i >> 4) & 1) << 1) | (((i >> 3) & 1) << 2)
                | (((i >> 2) & 1) << 3) | (((i >> 1) & 1) << 4) | ((i & 1) << 5);
    if (i < j) { float2 t = z[i]; z[i] = z[j]; z[j] = t; }
  }
  fft64_stage<SIGN, 0>(z, tw);
  fft64_stage<SIGN, 1>(z, tw);
  fft64_stage<SIGN, 2>(z, tw);
  fft64_stage<SIGN, 3>(z, tw);
  fft64_stage<SIGN, 4>(z, tw);
  fft64_stage<SIGN, 5>(z, tw);
}

// ---------------- init: twiddles ------------------------------------------
__global__ void k_init_tw(float2* tw64, float2* tw128) {
  int t = threadIdx.x;
  if (t < 32) {
    double th = -2.0 * PI_D * (double)t / 64.0;
    tw64[t] = make_float2((float)cos(th), (float)sin(th));
  }
  if (t < 65) {
    double th = -PI_D * (double)t / 64.0;
    tw128[t] = make_float2((float)cos(th), (float)sin(th));
  }
}

// ---------------- init: weights fp32 -> bf16, transposed [o][96] -----------
// dst flat: (((layer*8 + kb)*2 + ri)*96 + o)*96 + i ; src w[ri][kb][i][o]
__global__ __launch_bounds__(256) void k_wconv(
    const float* __restrict__ w1, const float* __restrict__ w2,
    unsigned short* __restrict__ wbf) {
  const int flat = blockIdx.x * 256 + threadIdx.x;   // < 294912
  const int i  = flat % 96;
  const int t2 = flat / 96;
  const int o  = t2 % 96;
  const int t3 = t2 / 96;
  const int ri = t3 & 1;
  const int t4 = t3 >> 1;
  const int kb = t4 & 7;
  const int layer = t4 >> 3;
  const float* w = layer ? w2 : w1;
  wbf[flat] = f2bfu(w[((size_t)(ri * 8 + kb) * 96 + i) * 96 + o]);
}

// ---------------- kernel 1: rfft along W, bf16 out -------------------------
__global__ __launch_bounds__(256) void k_rfft_w(
    const float* __restrict__ x,
    unsigned short* __restrict__ Sr, unsigned short* __restrict__ Si,
    const float2* __restrict__ tw64g, const float2* __restrict__ tw128g) {
  __shared__ float2 stw64[32];
  __shared__ float2 stw128[65];
  const int tid = threadIdx.x;
  if (tid < 32) stw64[tid]  = tw64g[tid];
  if (tid < 65) stw128[tid] = tw128g[tid];
  __syncthreads();
  const int blk = blockIdx.x;
  const int cc = blk % 3, bh = blk / 3;
  const int c = cc * 256 + tid;
  const float* xp = x + (size_t)bh * (W_ * C_) + c;
  float2 z[64];
  #pragma unroll
  for (int n = 0; n < 64; ++n) {
    z[n].x = xp[(size_t)(2 * n) * C_];
    z[n].y = xp[(size_t)(2 * n + 1) * C_];
  }
  fft64<-1>(z, stw64);
  const size_t obase = (size_t)bh * (WF * C_) + c;
  #pragma unroll
  for (int k = 0; k <= 64; ++k) {
    float2 a  = z[k & 63];
    float2 bq = z[(64 - k) & 63];
    float2 ze = make_float2(0.5f * (a.x + bq.x), 0.5f * (a.y - bq.y));
    float2 d  = make_float2(0.5f * (a.x - bq.x), 0.5f * (a.y + bq.y));
    float2 zo = make_float2(d.y, -d.x);
    float2 w  = stw128[k];
    float2 X  = make_float2(ze.x + w.x * zo.x - w.y * zo.y,
                            ze.y + w.x * zo.y + w.y * zo.x);
    Sr[obase + (size_t)k * C_] = f2bfu(X.x);
    Si[obase + (size_t)k * C_] = f2bfu(X.y);
  }
}

// ---------------- fused middle kernel: H-FFT -> complex MLP -> inv H-FFT ---
// one block per (b, wf, kb). LDS (shorts, stride 100 = 2-way-free banks):
//   [0,512)            twiddles
//   [512,26112)        panel  Pr[128][100] | Pi[128][100]   (51,200 B)
//   [26112,38912)      obuf   Or[64][100]  | Oi[64][100]    (25,600 B)
// total 77,824 B -> 2 blocks/CU (8 waves). Weights read from global (L2).
// FFT halves live in lanes l / l^32 of one wave; E/t swap via __shfl_xor(32)
// (no LDS scratch). Each wave owns 24 columns (c32<24), all 4 waves balanced.
static constexpr int LP_ = 512, LO_ = 26112;
static constexpr int L_BYTES = 38912 * 2;   // 77,824

__global__ __launch_bounds__(256, 2) void k_mid(
    unsigned short* __restrict__ Sr, unsigned short* __restrict__ Si,
    const unsigned short* __restrict__ wbf,
    const float* __restrict__ b1, const float* __restrict__ b2,
    const float2* __restrict__ tw64g, const float2* __restrict__ tw128g) {
  extern __shared__ unsigned short lds[];
  float2* stw64  = (float2*)lds;            // 32 float2
  float2* stw128 = (float2*)(lds + 128);    // 65 float2
  const int tid = threadIdx.x;
  if (tid < 32) stw64[tid]  = tw64g[tid];
  if (tid < 65) stw128[tid] = tw128g[tid];

  const int kb = blockIdx.x & 7;
  const int t2 = blockIdx.x >> 3;
  const int wf = t2 % 65, b = t2 / 65;
  const size_t hstr = (size_t)WF * C_;
  const size_t gb0  = ((size_t)b * H_ * WF + wf) * (size_t)C_ + (size_t)kb * 96;

  // ---- load spectrum panel: 6144 uint2 (Pr then Pi) ----
  #pragma unroll
  for (int it = 0; it < 24; ++it) {
    const int u = it * 256 + tid;
    const int p = (it >= 12);                      // wave-uniform plane select
    const int v = u - p * 3072;                    // 0..3071
    const int row = v / 24, cp = v - row * 24;     // 24 uint2 per row
    const unsigned short* src = (p ? Si : Sr) + gb0 + (size_t)row * hstr + cp * 4;
    *(uint2*)&lds[LP_ + p * 12800 + row * 100 + cp * 4] = *(const uint2*)src;
  }
  __syncthreads();   // S1: panel + twiddles ready

  const int wv = tid >> 6, lane = tid & 63;
  const int c32 = lane & 31, half = lane >> 5;
  const int ch = wv * 24 + c32;
  const bool act = c32 < 24;

  float2 z[64];
  // ---- forward 128-pt H-FFT (2 x fft64, register E/t swap via shfl) ----
  if (act) {
    #pragma unroll
    for (int n = 0; n < 64; ++n) {
      const int row = 2 * n + half;
      z[n].x = bf2f(lds[LP_ + row * 100 + ch]);
      z[n].y = bf2f(lds[LP_ + 12800 + row * 100 + ch]);
    }
    fft64<-1>(z, stw64);
    const float sc = 1.0f / 128.0f;
    #pragma unroll
    for (int k = 0; k < 64; ++k) {
      float2 mine = z[k];
      if (half) mine = cmul(stw128[k], mine);      // half1 holds t, half0 holds E
      float2 oth;
      oth.x = __shfl_xor(mine.x, 32, 64);
      oth.y = __shfl_xor(mine.y, 32, 64);
      float2 X = half ? make_float2(oth.x - mine.x, oth.y - mine.y)   // E - t
                      : make_float2(mine.x + oth.x, mine.y + oth.y);  // E + t
      const int row = k + half * 64;
      lds[LP_ + row * 100 + ch]         = f2bfu(X.x * sc);
      lds[LP_ + 12800 + row * 100 + ch] = f2bfu(X.y * sc);
    }
  }
  __syncthreads();   // S2: panel = H-freq spectrum (bf16)

  // ---- MLP: per 64-row m-tile, GEMM1 -> obuf -> GEMM2 -> panel ----
  const int mh = wv & 1, nh = wv >> 1;
  const int n32 = lane & 31, khalf = lane >> 5;
  const unsigned short* wL1 = wbf + (size_t)kb * 18432;
  const unsigned short* wL2 = wbf + (size_t)(8 + kb) * 18432;

  #pragma unroll 1
  for (int mt = 0; mt < 2; ++mt) {
    const int p0 = mt * 64;
    // GEMM1: A = panel rows [p0,p0+64), B = W1 (global/L2)
    floatx16 acc[3];
    #pragma unroll
    for (int t = 0; t < 3; ++t)
      #pragma unroll
      for (int e = 0; e < 16; ++e) acc[t][e] = 0.0f;
    const int arow = p0 + mh * 32 + n32;
    #pragma unroll
    for (int kk = 0; kk < 12; ++kk) {
      const int kr = kk >= 6;
      const int kloc = (kk - kr * 6) * 16 + khalf * 8;
      short8 afr = *(const short8*)&lds[LP_ + kr * 12800 + arow * 100 + kloc];
      const unsigned short* bb = wL1 + (kr != nh) * 9216;
      #pragma unroll
      for (int nt = 0; nt < 3; ++nt) {
        short8 bfr = *(const short8*)&bb[(nt * 32 + n32) * 96 + kloc];
        if (kr && !nh) {
          union { short8 s; int v[4]; } u; u.s = bfr;
          u.v[0] ^= 0x80008000; u.v[1] ^= 0x80008000;
          u.v[2] ^= 0x80008000; u.v[3] ^= 0x80008000;
          bfr = u.s;
        }
        acc[nt] = __builtin_amdgcn_mfma_f32_32x32x16_bf16(afr, bfr, acc[nt], 0, 0, 0);
      }
    }
    #pragma unroll
    for (int nt = 0; nt < 3; ++nt) {
      const int o = nt * 32 + n32;
      const float bs = b1[(nh * 8 + kb) * 96 + o];
      #pragma unroll
      for (int reg = 0; reg < 16; ++reg) {
        const int m0 = mh * 32 + (reg & 3) + 8 * (reg >> 2) + 4 * khalf;
        lds[LO_ + nh * 6400 + m0 * 100 + o] = f2bfu(softshrink(acc[nt][reg] + bs));
      }
    }
    __syncthreads();   // obuf(mt) ready; panel rows [p0,p0+64) fully read

    // GEMM2: A = obuf (local rows), B = W2 (global/L2)
    #pragma unroll
    for (int t = 0; t < 3; ++t)
      #pragma unroll
      for (int e = 0; e < 16; ++e) acc[t][e] = 0.0f;
    const int arow2 = mh * 32 + n32;
    #pragma unroll
    for (int kk = 0; kk < 12; ++kk) {
      const int kr = kk >= 6;
      const int kloc = (kk - kr * 6) * 16 + khalf * 8;
      short8 afr = *(const short8*)&lds[LO_ + kr * 6400 + arow2 * 100 + kloc];
      const unsigned short* bb = wL2 + (kr != nh) * 9216;
      #pragma unroll
      for (int nt = 0; nt < 3; ++nt) {
        short8 bfr = *(const short8*)&bb[(nt * 32 + n32) * 96 + kloc];
        if (kr && !nh) {
          union { short8 s; int v[4]; } u; u.s = bfr;
          u.v[0] ^= 0x80008000; u.v[1] ^= 0x80008000;
          u.v[2] ^= 0x80008000; u.v[3] ^= 0x80008000;
          bfr = u.s;
        }
        acc[nt] = __builtin_amdgcn_mfma_f32_32x32x16_bf16(afr, bfr, acc[nt], 0, 0, 0);
      }
    }
    #pragma unroll
    for (int nt = 0; nt < 3; ++nt) {
      const int o = nt * 32 + n32;
      const float bs = b2[(nh * 8 + kb) * 96 + o];
      #pragma unroll
      for (int reg = 0; reg < 16; ++reg) {
        const int m0 = mh * 32 + (reg & 3) + 8 * (reg >> 2) + 4 * khalf;
        lds[LP_ + nh * 12800 + (p0 + m0) * 100 + o] = f2bfu(softshrink(acc[nt][reg] + bs));
      }
    }
    __syncthreads();   // panel rows [p0,p0+64) = MLP out; obuf consumable again
  }

  // ---- inverse 128-pt H-FFT + global store (both halves store) ----
  if (act) {
    #pragma unroll
    for (int n = 0; n < 64; ++n) {
      const int row = 2 * n + half;
      z[n].x = bf2f(lds[LP_ + row * 100 + ch]);
      z[n].y = bf2f(lds[LP_ + 12800 + row * 100 + ch]);
    }
    fft64<1>(z, stw64);
    #pragma unroll
    for (int k = 0; k < 64; ++k) {
      float2 mine = z[k];
      if (half) { float2 w = stw128[k]; w.y = -w.y; mine = cmul(w, mine); }
      float2 oth;
      oth.x = __shfl_xor(mine.x, 32, 64);
      oth.y = __shfl_xor(mine.y, 32, 64);
      float2 X = half ? make_float2(oth.x - mine.x, oth.y - mine.y)
                      : make_float2(mine.x + oth.x, mine.y + oth.y);
      const size_t g = gb0 + (size_t)(k + half * 64) * hstr + ch;
      Sr[g] = f2bfu(X.x); Si[g] = f2bfu(X.y);
    }
  }
}

// ---------------- kernel 5: irfft along W + residual -----------------------
__global__ __launch_bounds__(256) void k_irfft_w(
    const unsigned short* __restrict__ Sr, const unsigned short* __restrict__ Si,
    const float* __restrict__ xin, float* __restrict__ y,
    const float2* __restrict__ tw64g, const float2* __restrict__ tw128g) {
  __shared__ float2 stw64[32];
  __shared__ float2 stw128[65];
  const int tid = threadIdx.x;
  if (tid < 32) stw64[tid]  = tw64g[tid];
  if (tid < 65) stw128[tid] = tw128g[tid];
  __syncthreads();
  const int blk = blockIdx.x;
  const int cc = blk % 3, bh = blk / 3;
  const int c = cc * 256 + tid;
  const size_t ibase = (size_t)bh * (WF * C_) + c;
  float2 z[64];
  {
    float x0r  = bf2f(Sr[ibase]);
    float x64r = bf2f(Sr[ibase + (size_t)64 * C_]);
    z[0] = make_float2(0.5f * (x0r + x64r), 0.5f * (x0r - x64r));
  }
  #pragma unroll
  for (int k = 1; k <= 32; ++k) {
    float2 a, b;
    a.x = bf2f(Sr[ibase + (size_t)k * C_]);        a.y = bf2f(Si[ibase + (size_t)k * C_]);
    b.x = bf2f(Sr[ibase + (size_t)(64 - k) * C_]); b.y = bf2f(Si[ibase + (size_t)(64 - k) * C_]);
    float2 s = make_float2(0.5f * (a.x + b.x), 0.5f * (a.y - b.y));
    float2 d = make_float2(0.5f * (a.x - b.x), 0.5f * (a.y + b.y));
    float2 w = stw128[k]; w.y = -w.y;
    float2 zo = cmul(w, d);
    z[k] = make_float2(s.x - zo.y, s.y + zo.x);
    if (k < 32) z[64 - k] = make_float2(s.x + zo.y, zo.x - s.y);
  }
  fft64<1>(z, stw64);
  const float* xb = xin + (size_t)bh * (W_ * C_) + c;
  float*       yb = y   + (size_t)bh * (W_ * C_) + c;
  #pragma unroll
  for (int n = 0; n < 64; ++n) {
    yb[(size_t)(2 * n) * C_]     = z[n].x * (1.0f / 64.0f) + xb[(size_t)(2 * n) * C_];
    yb[(size_t)(2 * n + 1) * C_] = z[n].y * (1.0f / 64.0f) + xb[(size_t)(2 * n + 1) * C_];
  }
}

extern "C" void kernel_launch(void* const* d_in, const int* in_sizes, int n_in,
                              void* d_out, int out_size, void* d_ws, size_t ws_size,
                              hipStream_t stream) {
  const float* x  = (const float*)d_in[0];
  const float* w1 = (const float*)d_in[1];
  const float* w2 = (const float*)d_in[2];
  const float* b1 = (const float*)d_in[3];
  const float* b2 = (const float*)d_in[4];
  float* y = (float*)d_out;

  float2* tw64  = (float2*)d_ws;
  float2* tw128 = tw64 + 32;
  unsigned short* wbf = (unsigned short*)((char*)d_ws + 1024);      // 294,912 shorts
  unsigned short* Sr  = (unsigned short*)((char*)d_ws + (1 << 20));
  unsigned short* Si  = Sr + PLANE;

  static bool attr_done = false;
  if (!attr_done) {
    hipFuncSetAttribute((const void*)k_mid,
                        hipFuncAttributeMaxDynamicSharedMemorySize, L_BYTES);
    attr_done = true;
  }

  k_init_tw<<<1, 128, 0, stream>>>(tw64, tw128);
  k_wconv<<<dim3(1152), dim3(256), 0, stream>>>(w1, w2, wbf);
  k_rfft_w<<<dim3(B_ * H_ * 3), dim3(256), 0, stream>>>(x, Sr, Si, tw64, tw128);
  k_mid<<<dim3(260 * 8), dim3(256), L_BYTES, stream>>>(Sr, Si, wbf, b1, b2, tw64, tw128);
  k_irfft_w<<<dim3(B_ * H_ * 3), dim3(256), 0, stream>>>(Sr, Si, x, y, tw64, tw128);
}